// Round 5
// baseline (303.113 us; speedup 1.0000x reference)
//
#include <hip/hip_runtime.h>
#include <math.h>

// Problem constants
#define BH 64      // (b=4) * (h=16) folded leading dim
#define NB 32      // buckets
#define BS 128     // bucket size
#define DHEAD 64   // head dim

typedef __attribute__((ext_vector_type(8))) short bf16x8;
typedef __attribute__((ext_vector_type(4))) float f32x4;

#define LDK 72     // padded row (u16) for Kh/Kl [128][72] — 144B rows, b128-aligned
#define LDW 68     // padded row (u32 words) for VT [64][68] — k-pairs packed
#define LDP 136    // padded row (u16) for P [128][136]

// ---------------- threefry2x32 (JAX partitionable PRNG), key = (0, 42) ----------------
__device__ __forceinline__ unsigned rotl32(unsigned x, int d) {
    return (x << d) | (x >> (32 - d));
}

__device__ __forceinline__ void threefry2x32(unsigned k0, unsigned k1,
                                             unsigned& x0, unsigned& x1) {
    const unsigned ks0 = k0, ks1 = k1, ks2 = k0 ^ k1 ^ 0x1BD11BDAu;
    const int r0[4] = {13, 15, 26, 6};
    const int r1[4] = {17, 29, 16, 24};
    x0 += ks0; x1 += ks1;
    #pragma unroll
    for (int i = 0; i < 4; i++) { x0 += x1; x1 = rotl32(x1, r0[i]); x1 ^= x0; }
    x0 += ks1; x1 += ks2 + 1u;
    #pragma unroll
    for (int i = 0; i < 4; i++) { x0 += x1; x1 = rotl32(x1, r1[i]); x1 ^= x0; }
    x0 += ks2; x1 += ks0 + 2u;
    #pragma unroll
    for (int i = 0; i < 4; i++) { x0 += x1; x1 = rotl32(x1, r0[i]); x1 ^= x0; }
    x0 += ks0; x1 += ks1 + 3u;
    #pragma unroll
    for (int i = 0; i < 4; i++) { x0 += x1; x1 = rotl32(x1, r1[i]); x1 ^= x0; }
    x0 += ks1; x1 += ks2 + 4u;
    #pragma unroll
    for (int i = 0; i < 4; i++) { x0 += x1; x1 = rotl32(x1, r0[i]); x1 ^= x0; }
    x0 += ks2; x1 += ks0 + 5u;
}

__device__ __forceinline__ float jax_uniform_part(unsigned f) {
    unsigned x0 = 0u, x1 = f;
    threefry2x32(0u, 42u, x0, x1);
    unsigned bits = x0 ^ x1;
    return __uint_as_float((bits >> 9) | 0x3F800000u) - 1.0f;
}

// ---------------- kernel 1: bucket key sums pl[bh][u][d], float4 reads ----------------
__global__ void __launch_bounds__(256)
pl_kernel(const float* __restrict__ k, float* __restrict__ pl) {
    int blk = blockIdx.x;               // bh*32 + u
    int rg = threadIdx.x >> 4;          // 16 row-groups of 8 rows
    int d4 = (threadIdx.x & 15) * 4;
    const float* kp = k + (size_t)blk * 8192 + (size_t)rg * 8 * 64 + d4;
    float4 s = {0.f, 0.f, 0.f, 0.f};
    #pragma unroll
    for (int i = 0; i < 8; i++) {
        float4 t = *(const float4*)(kp + i * 64);
        s.x += t.x; s.y += t.y; s.z += t.z; s.w += t.w;
    }
    __shared__ float red[16][64];
    *(float4*)&red[rg][d4] = s;
    __syncthreads();
    if (threadIdx.x < 64) {
        float acc = 0.f;
        #pragma unroll
        for (int g = 0; g < 16; g++) acc += red[g][threadIdx.x];
        pl[blk * 64 + threadIdx.x] = acc;
    }
}

// ---------------- kernel 2: routing; writes R' = exp(sinkhorn) + I ----------------
__global__ void route_kernel(const float* __restrict__ pl, const float* __restrict__ Wk,
                             float* __restrict__ Rout) {
    int bh = blockIdx.x;            // 64 blocks
    int h = bh & 15;
    int tid = threadIdx.x;          // 1024 threads
    int i = tid >> 5, j = tid & 31;

    __shared__ float plS[NB * DHEAD];
    __shared__ float T[32 * 33];
    __shared__ float colL[32];

    for (int x = tid; x < NB * DHEAD; x += 1024) plS[x] = pl[bh * NB * DHEAD + x];
    __syncthreads();

    float acc = 0.f;
    #pragma unroll 8
    for (int d2 = 0; d2 < DHEAD; d2++)
        acc += plS[i * DHEAD + d2] * Wk[(h * DHEAD + d2) * NB + j];

    unsigned f = (unsigned)bh * 1024u + (unsigned)i * 32u + (unsigned)j;
    float u = jax_uniform_part(f);
    float g = -logf(-logf(u + 1e-6f) + 1e-6f);
    float val = (acc + g) / 0.75f;

    for (int it = 0; it < 5; it++) {
        float m = val;
        #pragma unroll
        for (int off = 1; off < 32; off <<= 1) m = fmaxf(m, __shfl_xor(m, off, 32));
        float s = expf(val - m);
        #pragma unroll
        for (int off = 1; off < 32; off <<= 1) s += __shfl_xor(s, off, 32);
        val -= m + logf(s);

        T[i * 33 + j] = val;
        __syncthreads();
        float tv = T[j * 33 + i];
        float m2 = tv;
        #pragma unroll
        for (int off = 1; off < 32; off <<= 1) m2 = fmaxf(m2, __shfl_xor(m2, off, 32));
        float s2 = expf(tv - m2);
        #pragma unroll
        for (int off = 1; off < 32; off <<= 1) s2 += __shfl_xor(s2, off, 32);
        if (j == 0) colL[i] = m2 + logf(s2);
        __syncthreads();
        val -= colL[j];
    }
    Rout[bh * 1024 + i * 32 + j] = expf(val) + (i == j ? 1.0f : 0.0f);
}

// ---------------- kernel 3: K' = R' * K, output as split bf16 hi/lo planes ----------------
__global__ void __launch_bounds__(256)
mix_kernel(const float* __restrict__ k, const float* __restrict__ Rp,
           unsigned short* __restrict__ Kh, unsigned short* __restrict__ Kl) {
    __shared__ float X[32][260];
    int bh = blockIdx.x >> 5;       // 64 bh x 32 tiles
    int tile = blockIdx.x & 31;
    const size_t kbase = (size_t)bh * 262144;
    const int col0 = tile * 256;

    {   // stage: thread loads 8 float4 from row j = tid>>3
        int j = threadIdx.x >> 3;
        int cs = (threadIdx.x & 7) * 32;
        const float4* src = (const float4*)(k + kbase + (size_t)j * 8192 + col0 + cs);
        #pragma unroll
        for (int t = 0; t < 8; t++)
            *((float4*)&X[j][cs + 4 * t]) = src[t];
    }
    __syncthreads();

    const int col = threadIdx.x;
    float xv[32];
    #pragma unroll
    for (int j = 0; j < 32; j++) xv[j] = X[j][col];

    const float* Rb = Rp + bh * 1024;   // uniform -> s_load
    unsigned short* oh = Kh + kbase + col0 + col;
    unsigned short* ol = Kl + kbase + col0 + col;
    #pragma unroll 4
    for (int i = 0; i < 32; i++) {
        float acc = 0.f;
        #pragma unroll
        for (int j = 0; j < 32; j++) acc = fmaf(Rb[i * 32 + j], xv[j], acc);
        unsigned kb = __float_as_uint(acc);
        unsigned short hi = (unsigned short)(kb >> 16);
        float rem = acc - __uint_as_float(kb & 0xFFFF0000u);
        unsigned short lo = (unsigned short)(__float_as_uint(rem) >> 16);
        oh[(size_t)i * 8192] = hi;
        ol[(size_t)i * 8192] = lo;
    }
}

// ---------------- kernel 4: per-bucket attention via MFMA ----------------
// K' pre-split bf16 planes -> b128 copy staging. V stored transposed in LDS as
// packed u32 k-pairs -> PV B-fragment is ONE b128 read. P round-trip unchanged.
__global__ void __launch_bounds__(256)
attn_mfma_kernel(const float* __restrict__ q,
                 const unsigned short* __restrict__ Kh,
                 const unsigned short* __restrict__ Kl,
                 const float* __restrict__ v, float* __restrict__ out) {
    __shared__ __align__(16) unsigned char smem[2 * 128 * LDK * 2 + 64 * LDW * 4];
    unsigned short* KhS = (unsigned short*)smem;            // [128][LDK]
    unsigned short* KlS = KhS + 128 * LDK;                  // [128][LDK]
    unsigned*       VT  = (unsigned*)(smem + 2 * 128 * LDK * 2);  // [64][LDW]
    unsigned short* PbS = (unsigned short*)smem;            // [128][LDP], aliases Kh+Kl

    const int tid = threadIdx.x;
    const int w = tid >> 6, lane = tid & 63;
    const int quad = lane >> 4, l15 = lane & 15;
    const int row0 = 32 * w;
    const size_t base = (size_t)blockIdx.x * (BS * DHEAD);   // floats
    const size_t base2 = (size_t)blockIdx.x * (BS * DHEAD);  // u16 elements

    // ---- Q A-fragments (scaled by 1/8 exactly, split hi/lo bf16) ----
    bf16x8 qh[2][2], ql[2][2];
    #pragma unroll
    for (int ti = 0; ti < 2; ti++) {
        #pragma unroll
        for (int kk = 0; kk < 2; kk++) {
            const float* qp = q + base + (size_t)(row0 + 16 * ti + l15) * DHEAD
                              + kk * 32 + quad * 8;
            float4 a = ((const float4*)qp)[0];
            float4 b = ((const float4*)qp)[1];
            float f[8] = {a.x, a.y, a.z, a.w, b.x, b.y, b.z, b.w};
            #pragma unroll
            for (int j = 0; j < 8; j++) {
                float qs = f[j] * 0.125f;                 // exact (pow2)
                unsigned bits = __float_as_uint(qs);
                unsigned short hi = (unsigned short)(bits >> 16);
                float rem = qs - __uint_as_float(bits & 0xFFFF0000u);
                unsigned short lo = (unsigned short)(__float_as_uint(rem) >> 16);
                qh[ti][kk][j] = (short)hi;
                ql[ti][kk][j] = (short)lo;
            }
        }
    }

    // ---- stage K' planes: pure b128 copies ----
    {
        int r = tid >> 1, c0 = (tid & 1) * 32;
        const unsigned short* khg = Kh + base2 + (size_t)r * 64 + c0;
        const unsigned short* klg = Kl + base2 + (size_t)r * 64 + c0;
        #pragma unroll
        for (int x = 0; x < 4; x++) {
            bf16x8 th = *(const bf16x8*)(khg + 8 * x);
            bf16x8 tl = *(const bf16x8*)(klg + 8 * x);
            *(bf16x8*)&KhS[r * LDK + c0 + 8 * x] = th;
            *(bf16x8*)&KlS[r * LDK + c0 + 8 * x] = tl;
        }
    }

    // ---- stage V transposed, packed u32 k-pairs: VT[d][kpair] ----
    {
        int a = tid & 63;               // row pair: rows 2a, 2a+1
        int cs = (tid >> 6) * 16;       // 4 waves x 16 cols
        const float* v0p = v + base + (size_t)(2 * a) * 64 + cs;
        const float* v1p = v0p + 64;
        float r0[16], r1[16];
        #pragma unroll
        for (int t = 0; t < 4; t++) {
            ((float4*)r0)[t] = ((const float4*)v0p)[t];
            ((float4*)r1)[t] = ((const float4*)v1p)[t];
        }
        #pragma unroll
        for (int y = 0; y < 16; y++) {
            unsigned wd = ((__float_as_uint(r0[y]) + 0x8000u) >> 16)
                        | (((__float_as_uint(r1[y]) + 0x8000u) >> 16) << 16);
            VT[(cs + y) * LDW + a] = wd;
        }
    }
    __syncthreads();

    // ---- S = Qs K'^T : 2x8 tiles of 16x16, K=64 (2 chunks), 3 split terms ----
    f32x4 acc[2][8];
    #pragma unroll
    for (int ti = 0; ti < 2; ti++)
        #pragma unroll
        for (int tc = 0; tc < 8; tc++)
            acc[ti][tc] = (f32x4){0.f, 0.f, 0.f, 0.f};

    #pragma unroll
    for (int tc = 0; tc < 8; tc++) {
        const int jrow = 16 * tc + l15;
        bf16x8 bh0 = *(const bf16x8*)&KhS[jrow * LDK + 0  + quad * 8];
        bf16x8 bh1 = *(const bf16x8*)&KhS[jrow * LDK + 32 + quad * 8];
        bf16x8 bl0 = *(const bf16x8*)&KlS[jrow * LDK + 0  + quad * 8];
        bf16x8 bl1 = *(const bf16x8*)&KlS[jrow * LDK + 32 + quad * 8];
        #pragma unroll
        for (int ti = 0; ti < 2; ti++) {
            f32x4 c = acc[ti][tc];
            c = __builtin_amdgcn_mfma_f32_16x16x32_bf16(qh[ti][0], bh0, c, 0, 0, 0);
            c = __builtin_amdgcn_mfma_f32_16x16x32_bf16(qh[ti][1], bh1, c, 0, 0, 0);
            c = __builtin_amdgcn_mfma_f32_16x16x32_bf16(ql[ti][0], bh0, c, 0, 0, 0);
            c = __builtin_amdgcn_mfma_f32_16x16x32_bf16(ql[ti][1], bh1, c, 0, 0, 0);
            c = __builtin_amdgcn_mfma_f32_16x16x32_bf16(qh[ti][0], bl0, c, 0, 0, 0);
            c = __builtin_amdgcn_mfma_f32_16x16x32_bf16(qh[ti][1], bl1, c, 0, 0, 0);
            acc[ti][tc] = c;
        }
    }

    // ---- softmax over full 128 cols ----
    float mrow[2][4], lrow[2][4];
    #pragma unroll
    for (int ti = 0; ti < 2; ti++)
        #pragma unroll
        for (int r = 0; r < 4; r++) {
            float m = acc[ti][0][r];
            #pragma unroll
            for (int tc = 1; tc < 8; tc++) m = fmaxf(m, acc[ti][tc][r]);
            #pragma unroll
            for (int off = 1; off < 16; off <<= 1)
                m = fmaxf(m, __shfl_xor(m, off, 64));
            mrow[ti][r] = m;
        }
    #pragma unroll
    for (int ti = 0; ti < 2; ti++)
        #pragma unroll
        for (int r = 0; r < 4; r++) {
            float s = 0.f;
            #pragma unroll
            for (int tc = 0; tc < 8; tc++) {
                float p = __expf(acc[ti][tc][r] - mrow[ti][r]);
                acc[ti][tc][r] = p;
                s += p;
            }
            #pragma unroll
            for (int off = 1; off < 16; off <<= 1)
                s += __shfl_xor(s, off, 64);
            lrow[ti][r] = s;
        }

    __syncthreads();   // all waves done reading Kh/Kl before P overwrites them

    // ---- write P as bf16 into LDS ----
    #pragma unroll
    for (int ti = 0; ti < 2; ti++)
        #pragma unroll
        for (int tc = 0; tc < 8; tc++)
            #pragma unroll
            for (int r = 0; r < 4; r++) {
                int prow = row0 + 16 * ti + quad * 4 + r;
                unsigned pb = __float_as_uint(acc[ti][tc][r]);
                PbS[prow * LDP + 16 * tc + l15] = (unsigned short)((pb + 0x8000u) >> 16);
            }
    __syncthreads();

    // ---- O = P V : 2x4 tiles, K=128 (4 chunks); V B-frag = one b128 read ----
    f32x4 oacc[2][4];
    #pragma unroll
    for (int ti = 0; ti < 2; ti++)
        #pragma unroll
        for (int tc = 0; tc < 4; tc++)
            oacc[ti][tc] = (f32x4){0.f, 0.f, 0.f, 0.f};

    #pragma unroll
    for (int kc = 0; kc < 4; kc++) {
        bf16x8 aP[2];
        #pragma unroll
        for (int ti = 0; ti < 2; ti++)
            aP[ti] = *(const bf16x8*)&PbS[(row0 + 16 * ti + l15) * LDP + kc * 32 + quad * 8];
        #pragma unroll
        for (int tc = 0; tc < 4; tc++) {
            bf16x8 vb = *(const bf16x8*)&VT[(16 * tc + l15) * LDW + kc * 16 + quad * 4];
            #pragma unroll
            for (int ti = 0; ti < 2; ti++)
                oacc[ti][tc] = __builtin_amdgcn_mfma_f32_16x16x32_bf16(aP[ti], vb, oacc[ti][tc], 0, 0, 0);
        }
    }

    // ---- epilogue: normalize and store ----
    float inv[2][4];
    #pragma unroll
    for (int ti = 0; ti < 2; ti++)
        #pragma unroll
        for (int r = 0; r < 4; r++) inv[ti][r] = 1.0f / lrow[ti][r];

    #pragma unroll
    for (int ti = 0; ti < 2; ti++)
        #pragma unroll
        for (int tc = 0; tc < 4; tc++)
            #pragma unroll
            for (int r = 0; r < 4; r++) {
                int orow = row0 + 16 * ti + quad * 4 + r;
                out[base + (size_t)orow * DHEAD + 16 * tc + l15] = oacc[ti][tc][r] * inv[ti][r];
            }
}

extern "C" void kernel_launch(void* const* d_in, const int* in_sizes, int n_in,
                              void* d_out, int out_size, void* d_ws, size_t ws_size,
                              hipStream_t stream) {
    const float* q  = (const float*)d_in[0];
    const float* k  = (const float*)d_in[1];
    const float* v  = (const float*)d_in[2];
    const float* Wk = (const float*)d_in[3];
    float* out = (float*)d_out;

    // ws layout: Kh (16777216 u16) | Kl (16777216 u16) | pl (131072 f) | R' (65536 f)
    unsigned short* Kh = (unsigned short*)d_ws;
    unsigned short* Kl = Kh + (size_t)16777216;
    float* pl = (float*)(Kl + (size_t)16777216);
    float* R  = pl + (size_t)131072;

    pl_kernel<<<dim3(BH * NB), dim3(256), 0, stream>>>(k, pl);
    route_kernel<<<dim3(BH), dim3(1024), 0, stream>>>(pl, Wk, R);
    mix_kernel<<<dim3(BH * NB), dim3(256), 0, stream>>>(k, R, Kh, Kl);
    attn_mfma_kernel<<<dim3(BH * NB), dim3(256), 0, stream>>>(q, Kh, Kl, v, out);
}